// Round 20
// baseline (128.162 us; speedup 1.0000x reference)
//
#include <hip/hip_runtime.h>
#include <hip/hip_bf16.h>
#include <math.h>

#define BB 32
#define SS 20
#define LL 50
#define NN 40000
#define DD 64
#define TBL_ROWS 100001   // item_emb rows = NUM_ITEM+1
#define NSTRIPS  313      // ceil(40000/128)
#define QB 40             // score blocks per batch (8 strips each)

// Output layout (flat f32): scores (B,S,N) | hu (B,D) | hc (B,S,D) | attn (B,S,N)
#define OFF_SCORES 0
#define OFF_HU     (BB * SS * NN)
#define OFF_HC     (OFF_HU + BB * DD)
#define OFF_ATTN   (OFF_HC + BB * SS * DD)

// d_ws: [0,4096) spare | [4096, +12.8MB) bf16 item table
#define WS_TBL_OFF  4096
#define WS_NEEDED   ((size_t)WS_TBL_OFF + (size_t)TBL_ROWS * DD * 2)
#define CONV_BLOCKS ((TBL_ROWS * 16 + 511) / 512)             // 3126

typedef short  short8 __attribute__((ext_vector_type(8)));
typedef float  f32x16 __attribute__((ext_vector_type(16)));

// v_cvt_pk_bf16_f32: 2 f32 -> 1 u32, single instr
__device__ __forceinline__ unsigned cvtpk(float lo, float hi) {
    unsigned r;
    asm("v_cvt_pk_bf16_f32 %0, %1, %2" : "=v"(r) : "v"(lo), "v"(hi));
    return r;
}
__device__ __forceinline__ short8 pack8_hw(float4 x, float4 y) {
    uint4 iv;
    iv.x = cvtpk(x.x, x.y); iv.y = cvtpk(x.z, x.w);
    iv.z = cvtpk(y.x, y.y); iv.w = cvtpk(y.z, y.w);
    return __builtin_bit_cast(short8, iv);
}

// ---------------------------------------------------------------------------
// Launch 1: conv only (item_emb -> bf16 table). ~4-7us, BW-trivial.
// ---------------------------------------------------------------------------
__global__ __launch_bounds__(512) void conv_kernel(
    const float* __restrict__ src, unsigned int* __restrict__ dst)
{
    const int i = blockIdx.x * 512 + threadIdx.x;
    if (i >= TBL_ROWS * 16) return;
    float4 v = ((const float4*)src)[i];
    ((uint2*)dst)[i] = make_uint2(cvtpk(v.x, v.y), cvtpk(v.z, v.w));
}

// ---------------------------------------------------------------------------
// Launch 2 (fused, NO cross-block sync -- r18's spin-wait was a 5x disaster):
// each block = (batch b, strip-group q). The block REDOES its batch's prep
// in LDS (redundant across the 40 q-blocks, but fully parallel and hidden
// under other resident blocks' gather phases at 2 blocks/CU), then runs the
// r17 score path reading A-fragments/hcwc/c0 straight from LDS.
// hu/hc go to global only from q==0 blocks.
// ---------------------------------------------------------------------------
#define LOADB_TBL(dst, idx)                                              \
    {                                                                    \
        const unsigned short* brow_ = tbl + (size_t)(idx) * DD + hi * 8; \
        dst[0] = *(const short8*)(brow_ +  0);                           \
        dst[1] = *(const short8*)(brow_ + 16);                           \
        dst[2] = *(const short8*)(brow_ + 32);                           \
        dst[3] = *(const short8*)(brow_ + 48);                           \
    }
#define LOADB_F32(dst, idx)                                              \
    {                                                                    \
        const float* brow_ = item_emb + (size_t)(idx) * DD + hi * 8;     \
        const float4* p0_ = (const float4*)(brow_ +  0);                 \
        const float4* p1_ = (const float4*)(brow_ + 16);                 \
        const float4* p2_ = (const float4*)(brow_ + 32);                 \
        const float4* p3_ = (const float4*)(brow_ + 48);                 \
        dst[0] = pack8_hw(p0_[0], p0_[1]);                               \
        dst[1] = pack8_hw(p1_[0], p1_[1]);                               \
        dst[2] = pack8_hw(p2_[0], p2_[1]);                               \
        dst[3] = pack8_hw(p3_[0], p3_[1]);                               \
    }

template<bool USE_TBL>
__global__ __launch_bounds__(512, 4) void fused_kernel(
    const int* __restrict__ user_ids,
    const int* __restrict__ sess_item,
    const int* __restrict__ rcnt_item,
    const int* __restrict__ items,
    const float* __restrict__ item_emb,
    const float* __restrict__ user_emb,
    const float* __restrict__ user_emb2,
    const float* __restrict__ ue_w1,
    const float* __restrict__ ue_b1,
    const float* __restrict__ ue_w2,
    const float* __restrict__ ue_b2,
    const float* __restrict__ uenc_w,
    const float* __restrict__ uenc_b,
    const float* __restrict__ pred_w,
    const float* __restrict__ pred_b,
    const unsigned short* __restrict__ tbl,
    float* __restrict__ out)
{
    const int tid  = threadIdx.x;
    const int lane = tid & 63;
    const int wv   = tid >> 6;          // 0..7
    const int b    = blockIdx.y;
    const int q    = blockIdx.x;        // 0..QB-1

    __shared__ float w1_s[2 * DD][DD];                 // 32 KB
    __shared__ float uemb_s[DD];
    __shared__ float u2_s[DD];
    __shared__ float hs_s[LL][DD];                     // 12.8 KB
    __shared__ float wraw_s[LL];
    __shared__ float wn_s[LL];
    __shared__ float part_s[8][DD];                    // 2 KB
    __shared__ float hr_s[DD];
    __shared__ __align__(16) float hu_s[DD];
    __shared__ float e_s[SS][DD + 1];                  // 5.2 KB
    __shared__ float a_tmp[8][SS];
    __shared__ __align__(16) float hc_s[SS][DD];       // 5.1 KB
    __shared__ float hcwc_s[32];
    __shared__ float c0_s;

    // ================= prep (block-local) =================
    // stage: ue_w1 32KB, user embs, rcnt rows, sess rows
    for (int t = tid; t < 2 * DD * DD / 4; t += 512)
        ((float4*)&w1_s[0][0])[t] = ((const float4*)ue_w1)[t];
    const int uid = user_ids[b];
    if (tid < DD) {
        uemb_s[tid] = user_emb[(size_t)uid * DD + tid];
        u2_s[tid]   = user_emb2[(size_t)uid * DD + tid];
    }
    for (int t = tid; t < LL * DD; t += 512) {
        int l = t >> 6, d = t & 63;
        int idx = rcnt_item[b * LL + l];
        hs_s[l][d] = item_emb[(size_t)idx * DD + d];
    }
    for (int t = tid; t < SS * DD; t += 512) {
        int s = t >> 6, d = t & 63;
        int idx = sess_item[b * SS + s];
        e_s[s][d] = item_emb[(size_t)idx * DD + d];
    }
    if (tid < 12) hcwc_s[20 + tid] = 0.f;
    __syncthreads();

    // MLP logits (7 l's per wave, LDS operands)
    {
        float pu = 0.f;
        #pragma unroll 8
        for (int i = 0; i < DD; ++i) pu += uemb_s[i] * w1_s[i][lane];
        const float b1j = ue_b1[lane];
        const float w2j = ue_w2[lane];
        const float b2  = ue_b2[0];
        for (int l = wv; l < LL; l += 8) {
            float acc = pu + b1j;
            #pragma unroll 8
            for (int i = 0; i < DD; ++i) acc += hs_s[l][i] * w1_s[DD + i][lane];
            acc = fmaxf(acc, 0.f);
            float contrib = acc * w2j;
            #pragma unroll
            for (int off = 32; off; off >>= 1) contrib += __shfl_xor(contrib, off);
            if (lane == 0) wraw_s[l] = contrib + b2;
        }
    }
    __syncthreads();

    // masked softmax over L (wave 0)
    if (wv == 0) {
        float x = (lane < LL) ? wraw_s[lane] : -INFINITY;
        float m = x;
        #pragma unroll
        for (int off = 32; off; off >>= 1) m = fmaxf(m, __shfl_xor(m, off));
        float maskl = (lane < LL && rcnt_item[b * LL + lane] != 0) ? 1.f : 0.f;
        float e = (lane < LL) ? (__expf(x - m) + 1e-10f) * maskl : 0.f;
        float sum = e;
        #pragma unroll
        for (int off = 32; off; off >>= 1) sum += __shfl_xor(sum, off);
        if (lane < LL) wn_s[lane] = e / sum;
    }
    __syncthreads();

    // hr
    {
        float p = 0.f;
        for (int l = wv; l < LL; l += 8) p += wn_s[l] * hs_s[l][lane];
        part_s[wv][lane] = p;
    }
    __syncthreads();
    if (wv == 0) {
        float h = 0.f;
        #pragma unroll
        for (int w = 0; w < 8; ++w) h += part_s[w][lane];
        hr_s[lane] = h;
    }
    __syncthreads();

    // hu
    {
        float p = 0.f;
        for (int i = wv * 16; i < wv * 16 + 16; ++i) {
            float c = (i < DD) ? u2_s[i] : hr_s[i - DD];
            p += c * uenc_w[i * DD + lane];
        }
        part_s[wv][lane] = p;
    }
    __syncthreads();
    if (wv == 0) {
        float hu = uenc_b[lane];
        #pragma unroll
        for (int w = 0; w < 8; ++w) hu += part_s[w][lane];
        hu_s[lane] = hu;
        if (q == 0) out[OFF_HU + b * DD + lane] = hu;
    }
    __syncthreads();

    // c0 (wave 7, concurrent with session attn on waves 0..6's rows)
    if (wv == 7) {
        float p = hu_s[lane] * pred_w[lane];
        #pragma unroll
        for (int off = 32; off; off >>= 1) p += __shfl_xor(p, off);
        if (lane == 0) c0_s = p + pred_b[0];
    }

    // session self-attention -> hc (a_tmp[wv] wave-local) + hcwc
    {
        const float wcj = pred_w[DD + lane];
        for (int s = wv; s < SS; s += 8) {
            const int t = lane;
            float lt = -INFINITY;
            float maskt = 0.f;
            if (t < SS) {
                float dot = 0.f;
                #pragma unroll 8
                for (int d = 0; d < DD; ++d) dot += e_s[s][d] * e_s[t][d];
                lt = dot * 0.125f;
                maskt = (sess_item[b * SS + t] != 0) ? 1.f : 0.f;
            }
            float srow = (sess_item[b * SS + s] != 0) ? 1.f : 0.f;
            float m = lt;
            #pragma unroll
            for (int off = 32; off; off >>= 1) m = fmaxf(m, __shfl_xor(m, off));
            float e = (t < SS) ? (__expf(lt - m) + 1e-10f) * (maskt * srow) : 0.f;
            float sum = e;
            #pragma unroll
            for (int off = 32; off; off >>= 1) sum += __shfl_xor(sum, off);
            if (t < SS) a_tmp[wv][t] = e / sum;
            float hc = 0.f;
            #pragma unroll
            for (int tt = 0; tt < SS; ++tt) hc += a_tmp[wv][tt] * e_s[tt][lane];
            hc_s[s][lane] = hc;
            if (q == 0) out[OFF_HC + (size_t)(b * SS + s) * DD + lane] = hc;
            float p = hc * wcj;
            #pragma unroll
            for (int off = 32; off; off >>= 1) p += __shfl_xor(p, off);
            if (lane == 0) hcwc_s[s] = p;
        }
    }
    __syncthreads();

    // ================= score (r17 structure, operands from LDS) =================
    const int strip = q * 8 + wv;
    if (strip >= NSTRIPS) return;                   // wave-uniform
    const int n0 = strip * 128;
    const int c  = lane & 31;
    const int hi = lane >> 5;

    // A fragments from LDS rows (hc / hu / wv-global / zero)
    short8 aF[4];
    {
        const float* rp = (c < SS) ? &hc_s[c][0]
                        : (c == 20) ? &hu_s[0]
                        : (c == 21) ? (pred_w + 2 * DD) : nullptr;
        #pragma unroll
        for (int t = 0; t < 4; ++t) {
            if (rp) {
                const float4* p4 = (const float4*)(rp + t * 16 + hi * 8);
                aF[t] = pack8_hw(p4[0], p4[1]);
            } else {
                uint4 z = make_uint4(0, 0, 0, 0);
                aF[t] = __builtin_bit_cast(short8, z);
            }
        }
    }

    float hcr[12];
    #pragma unroll
    for (int r = 0; r < 12; ++r) {
        int row = (r & 3) + 8 * (r >> 2) + 4 * hi;
        hcr[r] = hcwc_s[row];
    }
    const float c0v = c0_s;

    int idxT[4];
    #pragma unroll
    for (int T = 0; T < 4; ++T) {
        int nt = n0 + T * 32;
        idxT[T] = (nt < NN) ? items[b * NN + nt + c] : 0;
    }

    short8 bf0[4], bf1[4], bf2[4], bf3[4];
    if (USE_TBL) {
        LOADB_TBL(bf0, idxT[0]); LOADB_TBL(bf1, idxT[1]);
        LOADB_TBL(bf2, idxT[2]); LOADB_TBL(bf3, idxT[3]);
    } else {
        LOADB_F32(bf0, idxT[0]); LOADB_F32(bf1, idxT[1]);
        LOADB_F32(bf2, idxT[2]); LOADB_F32(bf3, idxT[3]);
    }

    #pragma unroll
    for (int T = 0; T < 4; ++T) {
        const int n0t = n0 + T * 32;
        if (n0t >= NN) continue;

        f32x16 acc = {0.f,0.f,0.f,0.f,0.f,0.f,0.f,0.f,0.f,0.f,0.f,0.f,0.f,0.f,0.f,0.f};
        #pragma unroll
        for (int t = 0; t < 4; ++t) {
            const short8 bfr = (T == 0) ? bf0[t] : (T == 1) ? bf1[t] : (T == 2) ? bf2[t] : bf3[t];
            acc = __builtin_amdgcn_mfma_f32_32x32x16_bf16(aF[t], bfr, acc, 0, 0, 0);
        }

        const float huv = __shfl(acc[8], 32 + c);
        const float vwv = __shfl(acc[9], 32 + c);
        const float gb  = c0v + vwv;

        float* sc = out + OFF_SCORES + (size_t)b * SS * NN + n0t + c;
        float* at = out + OFF_ATTN   + (size_t)b * SS * NN + n0t + c;

        #pragma unroll
        for (int r = 0; r < 12; ++r) {
            if (!(hi && r >= 8)) {                  // hi half: regs 8..11 = rows 20..23
                int row = (r & 3) + 8 * (r >> 2) + 4 * hi;
                float hcv  = acc[r];
                float g    = gb + hcr[r];
                float attn = 1.f / (1.f + __expf(-g));
                float scv  = hcv + attn * (huv - hcv);
                sc[(size_t)row * NN] = scv;
                at[(size_t)row * NN] = attn;
            }
        }
    }
}

extern "C" void kernel_launch(void* const* d_in, const int* in_sizes, int n_in,
                              void* d_out, int out_size, void* d_ws, size_t ws_size,
                              hipStream_t stream) {
    const int*   user_ids  = (const int*)d_in[0];
    const int*   sess_item = (const int*)d_in[1];
    const int*   rcnt_item = (const int*)d_in[2];
    const int*   items     = (const int*)d_in[3];
    const float* item_emb  = (const float*)d_in[4];
    const float* user_emb  = (const float*)d_in[5];
    const float* user_emb2 = (const float*)d_in[6];
    const float* ue_w1     = (const float*)d_in[7];
    const float* ue_b1     = (const float*)d_in[8];
    const float* ue_w2     = (const float*)d_in[9];
    const float* ue_b2     = (const float*)d_in[10];
    const float* uenc_w    = (const float*)d_in[11];
    const float* uenc_b    = (const float*)d_in[12];
    const float* pred_w    = (const float*)d_in[13];
    const float* pred_b    = (const float*)d_in[14];
    float* out = (float*)d_out;

    unsigned short* tbl = (unsigned short*)((char*)d_ws + WS_TBL_OFF);
    const bool use_tbl = (ws_size >= WS_NEEDED);

    if (use_tbl) {
        hipLaunchKernelGGL(conv_kernel, dim3(CONV_BLOCKS), dim3(512), 0, stream,
                           item_emb, (unsigned int*)tbl);
    }

    const dim3 grid(QB, BB);                        // 40 x 32 = 1280 blocks
    if (use_tbl) {
        hipLaunchKernelGGL((fused_kernel<true>), grid, dim3(512), 0, stream,
                           user_ids, sess_item, rcnt_item, items, item_emb,
                           user_emb, user_emb2, ue_w1, ue_b1, ue_w2, ue_b2,
                           uenc_w, uenc_b, pred_w, pred_b, tbl, out);
    } else {
        hipLaunchKernelGGL((fused_kernel<false>), grid, dim3(512), 0, stream,
                           user_ids, sess_item, rcnt_item, items, item_emb,
                           user_emb, user_emb2, ue_w1, ue_b1, ue_w2, ue_b2,
                           uenc_w, uenc_b, pred_w, pred_b, tbl, out);
    }
}

// Round 21
// 81.808 us; speedup vs baseline: 1.5666x; 1.5666x over previous
//
#include <hip/hip_runtime.h>
#include <hip/hip_bf16.h>
#include <math.h>

#define BB 32
#define SS 20
#define LL 50
#define NN 40000
#define DD 64
#define TBL_ROWS 100001   // item_emb rows = NUM_ITEM+1

// Output layout (flat f32): scores (B,S,N) | hu (B,D) | hc (B,S,D) | attn (B,S,N)
#define OFF_SCORES 0
#define OFF_HU     (BB * SS * NN)
#define OFF_HC     (OFF_HU + BB * DD)
#define OFF_ATTN   (OFF_HC + BB * SS * DD)

// d_ws layout: [0,4096) hcwc (32b x 32 f32) | [4096,+128K) comb bf16 | [135168,+12.8MB) bf16 table
#define WS_COMB_OFF 4096
#define WS_TBL_OFF  (WS_COMB_OFF + BB * 32 * DD * 2)          // 135168 (128B-aligned)
#define WS_NEEDED   ((size_t)WS_TBL_OFF + (size_t)TBL_ROWS * DD * 2)
#define CONV_BLOCKS ((TBL_ROWS * 16 + 511) / 512)             // 3126 (512-thread blocks)

typedef short  short8 __attribute__((ext_vector_type(8)));
typedef float  f32x16 __attribute__((ext_vector_type(16)));

__device__ __forceinline__ unsigned short f2bf(float x) {   // RNE f32->bf16 (cold)
    unsigned u = __float_as_uint(x);
    return (unsigned short)((u + 0x7fffu + ((u >> 16) & 1u)) >> 16);
}
// v_cvt_pk_bf16_f32: 2 f32 -> 1 u32, single instr
__device__ __forceinline__ unsigned cvtpk(float lo, float hi) {
    unsigned r;
    asm("v_cvt_pk_bf16_f32 %0, %1, %2" : "=v"(r) : "v"(lo), "v"(hi));
    return r;
}
__device__ __forceinline__ short8 pack8_hw(float4 x, float4 y) {
    uint4 iv;
    iv.x = cvtpk(x.x, x.y); iv.y = cvtpk(x.z, x.w);
    iv.z = cvtpk(y.x, y.y); iv.w = cvtpk(y.z, y.w);
    return __builtin_bit_cast(short8, iv);
}

// ---------------------------------------------------------------------------
// Setup (r17, byte-exact revert -- best measured config, 82.6us total).
// r18 (spin-wait fusion): 5x disaster. r20 (redundant-prep fusion): +45us
// regression. The 2-launch structure stands.
//   blocks [0,32):  prepA  -- user path (8 waves, w1 LDS-resident)
//   blocks [32,64): prepB  -- session attention (8 waves)
//   blocks [64,+):  conv   -- item_emb -> bf16 table
// ---------------------------------------------------------------------------
__global__ __launch_bounds__(512) void setup_kernel(
    const int* __restrict__ user_ids,
    const int* __restrict__ sess_item,
    const int* __restrict__ rcnt_item,
    const float* __restrict__ item_emb,
    const float* __restrict__ user_emb,
    const float* __restrict__ user_emb2,
    const float* __restrict__ ue_w1,
    const float* __restrict__ ue_b1,
    const float* __restrict__ ue_w2,
    const float* __restrict__ ue_b2,
    const float* __restrict__ uenc_w,
    const float* __restrict__ uenc_b,
    const float* __restrict__ pred_w,
    const float* __restrict__ pred_b,
    float* __restrict__ out,
    float* __restrict__ hcwc_ws,
    unsigned short* __restrict__ comb_bf,
    unsigned int* __restrict__ tbl_dst,
    int has_tbl)
{
    const int tid  = threadIdx.x;
    const int lane = tid & 63;
    const int wv   = tid >> 6;          // 0..7

    __shared__ float w1_s[2 * DD][DD];  // ue_w1: 32 KB
    __shared__ float uemb_s[DD];
    __shared__ float u2_s[DD];
    __shared__ float hs_s[LL][DD];
    __shared__ float wraw_s[LL];
    __shared__ float wn_s[LL];
    __shared__ float part_s[8][DD];
    __shared__ float hr_s[DD];
    __shared__ float hu_s[DD];
    __shared__ float e_s[SS][DD + 1];
    __shared__ float a_tmp[8][SS];

    if (blockIdx.x >= 64u) {
        // ---- conv ----
        const int i = (blockIdx.x - 64) * 512 + tid;
        if (i < TBL_ROWS * 16) {
            float4 v = ((const float4*)item_emb)[i];
            ((uint2*)tbl_dst)[i] = make_uint2(cvtpk(v.x, v.y), cvtpk(v.z, v.w));
        }
        return;
    }

    if (blockIdx.x < 32u) {
        // ================= prepA: user path (8 waves) =================
        const int b = blockIdx.x;

        for (int t = tid; t < 2 * DD * DD / 4; t += 512)
            ((float4*)&w1_s[0][0])[t] = ((const float4*)ue_w1)[t];

        const int uid = user_ids[b];
        if (tid < DD) {
            uemb_s[tid] = user_emb[(size_t)uid * DD + tid];
            u2_s[tid]   = user_emb2[(size_t)uid * DD + tid];
        }
        for (int t = tid; t < LL * DD; t += 512) {
            int l = t >> 6, d = t & 63;
            int idx = rcnt_item[b * LL + l];
            hs_s[l][d] = item_emb[(size_t)idx * DD + d];
        }
        __syncthreads();

        // phase 2: attention MLP logits (LDS operands; 7 l's per wave)
        float pu = 0.f;
        #pragma unroll 8
        for (int i = 0; i < DD; ++i) pu += uemb_s[i] * w1_s[i][lane];
        const float b1j = ue_b1[lane];
        const float w2j = ue_w2[lane];
        const float b2  = ue_b2[0];
        for (int l = wv; l < LL; l += 8) {
            float acc = pu + b1j;
            #pragma unroll 8
            for (int i = 0; i < DD; ++i) acc += hs_s[l][i] * w1_s[DD + i][lane];
            acc = fmaxf(acc, 0.f);
            float contrib = acc * w2j;
            #pragma unroll
            for (int off = 32; off; off >>= 1) contrib += __shfl_xor(contrib, off);
            if (lane == 0) wraw_s[l] = contrib + b2;
        }
        __syncthreads();

        // phase 3: masked softmax over L (wave 0)
        if (wv == 0) {
            float x = (lane < LL) ? wraw_s[lane] : -INFINITY;
            float m = x;
            #pragma unroll
            for (int off = 32; off; off >>= 1) m = fmaxf(m, __shfl_xor(m, off));
            float maskl = (lane < LL && rcnt_item[b * LL + lane] != 0) ? 1.f : 0.f;
            float e = (lane < LL) ? (__expf(x - m) + 1e-10f) * maskl : 0.f;
            float sum = e;
            #pragma unroll
            for (int off = 32; off; off >>= 1) sum += __shfl_xor(sum, off);
            if (lane < LL) wn_s[lane] = e / sum;
        }
        __syncthreads();

        // phase 4: hr (8-wave partial reduce)
        {
            float p = 0.f;
            for (int l = wv; l < LL; l += 8) p += wn_s[l] * hs_s[l][lane];
            part_s[wv][lane] = p;
        }
        __syncthreads();
        if (wv == 0) {
            float h = 0.f;
            #pragma unroll
            for (int w = 0; w < 8; ++w) h += part_s[w][lane];
            hr_s[lane] = h;
        }
        __syncthreads();

        // phase 5: hu (16 i's per wave)
        {
            float p = 0.f;
            for (int i = wv * 16; i < wv * 16 + 16; ++i) {
                float c = (i < DD) ? u2_s[i] : hr_s[i - DD];
                p += c * uenc_w[i * DD + lane];
            }
            part_s[wv][lane] = p;
        }
        __syncthreads();
        if (wv == 0) {
            float hu = uenc_b[lane];
            #pragma unroll
            for (int w = 0; w < 8; ++w) hu += part_s[w][lane];
            hu_s[lane] = hu;
            out[OFF_HU + b * DD + lane] = hu;
        }
        __syncthreads();

        // c0 -> slot 24 (wave 1)
        if (wv == 1) {
            float p = hu_s[lane] * pred_w[lane];
            #pragma unroll
            for (int off = 32; off; off >>= 1) p += __shfl_xor(p, off);
            if (lane == 0) hcwc_ws[b * 32 + 24] = p + pred_b[0];
        }
        if (tid < 11) {
            int sl = (tid < 4) ? (20 + tid) : (21 + tid);   // 20..23, 25..31
            hcwc_ws[b * 32 + sl] = 0.f;
        }
        if (has_tbl) {
            for (int t = tid; t < 12 * DD; t += 512) {
                int row = 20 + (t >> 6), d = t & 63;
                float v = (row == 20) ? hu_s[d]
                        : (row == 21) ? pred_w[2 * DD + d] : 0.f;
                comb_bf[b * (32 * DD) + row * DD + d] = f2bf(v);
            }
        }
        return;
    }

    // ================= prepB: session self-attention (8 waves) =================
    {
        const int b = blockIdx.x - 32;

        for (int t = tid; t < SS * DD; t += 512) {
            int s = t >> 6, d = t & 63;
            int idx = sess_item[b * SS + s];
            e_s[s][d] = item_emb[(size_t)idx * DD + d];
        }
        __syncthreads();

        const float wcj = pred_w[DD + lane];
        for (int s = wv; s < SS; s += 8) {
            const int t = lane;
            float lt = -INFINITY;
            float maskt = 0.f;
            if (t < SS) {
                float dot = 0.f;
                #pragma unroll 8
                for (int d = 0; d < DD; ++d) dot += e_s[s][d] * e_s[t][d];
                lt = dot * 0.125f;
                maskt = (sess_item[b * SS + t] != 0) ? 1.f : 0.f;
            }
            float srow = (sess_item[b * SS + s] != 0) ? 1.f : 0.f;
            float m = lt;
            #pragma unroll
            for (int off = 32; off; off >>= 1) m = fmaxf(m, __shfl_xor(m, off));
            float e = (t < SS) ? (__expf(lt - m) + 1e-10f) * (maskt * srow) : 0.f;
            float sum = e;
            #pragma unroll
            for (int off = 32; off; off >>= 1) sum += __shfl_xor(sum, off);
            if (t < SS) a_tmp[wv][t] = e / sum;
            float hc = 0.f;
            #pragma unroll
            for (int tt = 0; tt < SS; ++tt) hc += a_tmp[wv][tt] * e_s[tt][lane];

            out[OFF_HC + (size_t)(b * SS + s) * DD + lane] = hc;
            if (has_tbl) comb_bf[b * (32 * DD) + s * DD + lane] = f2bf(hc);
            float p = hc * wcj;
            #pragma unroll
            for (int off = 32; off; off >>= 1) p += __shfl_xor(p, off);
            if (lane == 0) hcwc_ws[b * 32 + s] = p;
        }
        return;
    }
}

// ---------------------------------------------------------------------------
// Score (MFMA): r13/r17 untransposed structure, byte-exact. 2x128B contiguous
// stores per instr (no write amplification); ping-pong B prefetch; ~63.7us
// measured -- pinned by random-gather line-miss throughput (8 micro-
// experiments all null).
// ---------------------------------------------------------------------------
#define LOADB_TBL(dst, idx)                                              \
    {                                                                    \
        const unsigned short* brow_ = tbl + (size_t)(idx) * DD + hi * 8; \
        dst[0] = *(const short8*)(brow_ +  0);                           \
        dst[1] = *(const short8*)(brow_ + 16);                           \
        dst[2] = *(const short8*)(brow_ + 32);                           \
        dst[3] = *(const short8*)(brow_ + 48);                           \
    }
#define LOADB_F32(dst, idx)                                              \
    {                                                                    \
        const float* brow_ = item_emb + (size_t)(idx) * DD + hi * 8;     \
        const float4* p0_ = (const float4*)(brow_ +  0);                 \
        const float4* p1_ = (const float4*)(brow_ + 16);                 \
        const float4* p2_ = (const float4*)(brow_ + 32);                 \
        const float4* p3_ = (const float4*)(brow_ + 48);                 \
        dst[0] = pack8_hw(p0_[0], p0_[1]);                               \
        dst[1] = pack8_hw(p1_[0], p1_[1]);                               \
        dst[2] = pack8_hw(p2_[0], p2_[1]);                               \
        dst[3] = pack8_hw(p3_[0], p3_[1]);                               \
    }

template<bool USE_TBL>
__global__ __launch_bounds__(256, 4) void score_kernel(
    const int* __restrict__ items,
    const float* __restrict__ item_emb,
    const unsigned short* __restrict__ tbl,
    const unsigned short* __restrict__ comb_bf,
    const float* __restrict__ pred_w,
    const float* __restrict__ hcwc_ws,
    float* __restrict__ out)
{
    const int tid   = threadIdx.x;
    const int lane  = tid & 63;
    const int wv    = tid >> 6;
    const int b     = blockIdx.y;
    const int strip = blockIdx.x * 4 + wv;          // 128-col strip
    const int n0    = strip * 128;
    if (n0 >= NN) return;                           // wave-uniform exit
    const int c  = lane & 31;
    const int hi = lane >> 5;

    // ---- A fragments (comb rows, bf16 pre-packed by prep) ----
    short8 aF[4];
    if (USE_TBL) {
        const unsigned short* arow = comb_bf + b * (32 * DD) + c * DD + hi * 8;
        #pragma unroll
        for (int t = 0; t < 4; ++t) aF[t] = *(const short8*)(arow + t * 16);
    } else {
        const float* rp = (c < SS) ? (out + OFF_HC + ((size_t)b * SS + c) * DD)
                        : (c == 20) ? (out + OFF_HU + (size_t)b * DD)
                        : (c == 21) ? (pred_w + 2 * DD) : nullptr;
        #pragma unroll
        for (int t = 0; t < 4; ++t) {
            if (rp) {
                const float4* p4 = (const float4*)(rp + t * 16 + hi * 8);
                aF[t] = pack8_hw(p4[0], p4[1]);
            } else {
                uint4 z = make_uint4(0, 0, 0, 0);
                aF[t] = __builtin_bit_cast(short8, z);
            }
        }
    }

    // per-lane hcwc for the 12 C-regs holding score rows; c0 (uniform)
    float hcr[12];
    #pragma unroll
    for (int r = 0; r < 12; ++r) {
        int row = (r & 3) + 8 * (r >> 2) + 4 * hi;
        hcr[r] = hcwc_ws[b * 32 + row];
    }
    const float c0v = hcwc_ws[b * 32 + 24];

    int idxT[4];
    #pragma unroll
    for (int T = 0; T < 4; ++T) {
        int nt = n0 + T * 32;
        idxT[T] = (nt < NN) ? items[b * NN + nt + c] : 0;
    }

    // ---- prefetch ALL 4 tiles' B fragments (16 gathers in flight) ----
    short8 bf0[4], bf1[4], bf2[4], bf3[4];
    if (USE_TBL) {
        LOADB_TBL(bf0, idxT[0]); LOADB_TBL(bf1, idxT[1]);
        LOADB_TBL(bf2, idxT[2]); LOADB_TBL(bf3, idxT[3]);
    } else {
        LOADB_F32(bf0, idxT[0]); LOADB_F32(bf1, idxT[1]);
        LOADB_F32(bf2, idxT[2]); LOADB_F32(bf3, idxT[3]);
    }

    #pragma unroll
    for (int T = 0; T < 4; ++T) {
        const int n0t = n0 + T * 32;
        if (n0t >= NN) continue;

        f32x16 acc = {0.f,0.f,0.f,0.f,0.f,0.f,0.f,0.f,0.f,0.f,0.f,0.f,0.f,0.f,0.f,0.f};
        #pragma unroll
        for (int t = 0; t < 4; ++t) {
            const short8 bfr = (T == 0) ? bf0[t] : (T == 1) ? bf1[t] : (T == 2) ? bf2[t] : bf3[t];
            acc = __builtin_amdgcn_mfma_f32_32x32x16_bf16(aF[t], bfr, acc, 0, 0, 0);
        }

        // rows 20 (huv) / 21 (vwv): regs 8/9 on the hi half
        const float huv = __shfl(acc[8], 32 + c);
        const float vwv = __shfl(acc[9], 32 + c);
        const float gb  = c0v + vwv;

        float* sc = out + OFF_SCORES + (size_t)b * SS * NN + n0t + c;
        float* at = out + OFF_ATTN   + (size_t)b * SS * NN + n0t + c;

        #pragma unroll
        for (int r = 0; r < 12; ++r) {
            if (!(hi && r >= 8)) {                  // hi half: regs 8..11 = rows 20..23
                int row = (r & 3) + 8 * (r >> 2) + 4 * hi;
                float hcv  = acc[r];
                float g    = gb + hcr[r];
                float attn = 1.f / (1.f + __expf(-g));
                float scv  = hcv + attn * (huv - hcv);
                sc[(size_t)row * NN] = scv;
                at[(size_t)row * NN] = attn;
            }
        }
    }
}

extern "C" void kernel_launch(void* const* d_in, const int* in_sizes, int n_in,
                              void* d_out, int out_size, void* d_ws, size_t ws_size,
                              hipStream_t stream) {
    const int*   user_ids  = (const int*)d_in[0];
    const int*   sess_item = (const int*)d_in[1];
    const int*   rcnt_item = (const int*)d_in[2];
    const int*   items     = (const int*)d_in[3];
    const float* item_emb  = (const float*)d_in[4];
    const float* user_emb  = (const float*)d_in[5];
    const float* user_emb2 = (const float*)d_in[6];
    const float* ue_w1     = (const float*)d_in[7];
    const float* ue_b1     = (const float*)d_in[8];
    const float* ue_w2     = (const float*)d_in[9];
    const float* ue_b2     = (const float*)d_in[10];
    const float* uenc_w    = (const float*)d_in[11];
    const float* uenc_b    = (const float*)d_in[12];
    const float* pred_w    = (const float*)d_in[13];
    const float* pred_b    = (const float*)d_in[14];
    float* out = (float*)d_out;

    float*          hcwc_ws = (float*)d_ws;
    unsigned short* comb_bf = (unsigned short*)((char*)d_ws + WS_COMB_OFF);
    unsigned short* tbl     = (unsigned short*)((char*)d_ws + WS_TBL_OFF);
    const bool use_tbl = (ws_size >= WS_NEEDED);
    const int  convB   = use_tbl ? CONV_BLOCKS : 0;

    hipLaunchKernelGGL(setup_kernel, dim3(64 + convB), dim3(512), 0, stream,
                       user_ids, sess_item, rcnt_item, item_emb, user_emb, user_emb2,
                       ue_w1, ue_b1, ue_w2, ue_b2, uenc_w, uenc_b, pred_w, pred_b,
                       out, hcwc_ws, comb_bf, (unsigned int*)tbl,
                       use_tbl ? 1 : 0);

    const int nstrips = (NN + 127) / 128;           // 313
    const dim3 grid((nstrips + 3) / 4, BB);         // 79 x 32
    if (use_tbl) {
        hipLaunchKernelGGL((score_kernel<true>), grid, dim3(256), 0, stream,
                           items, item_emb, tbl, comb_bf, pred_w, hcwc_ws, out);
    } else {
        hipLaunchKernelGGL((score_kernel<false>), grid, dim3(256), 0, stream,
                           items, item_emb, tbl, comb_bf, pred_w, hcwc_ws, out);
    }
}